// Round 2
// baseline (153.419 us; speedup 1.0000x reference)
//
#include <hip/hip_runtime.h>
#include <hip/hip_bf16.h>

#define NN 8192
#define DD 128

typedef __attribute__((ext_vector_type(4))) float f32x4;
typedef __attribute__((ext_vector_type(8))) short bf16x8;

__device__ __forceinline__ short f2bf(float f) {
  __hip_bfloat16 h = __float2bfloat16(f);
  return __builtin_bit_cast(short, h);
}

// ---------------------------------------------------------------------------
// Kernel 1: yT[n][k] = sum_d x[k][d] * W[d][n]   (bf16, transposed)
// ---------------------------------------------------------------------------
__global__ __launch_bounds__(256) void xw_kernel(
    const float* __restrict__ x, const float* __restrict__ W,
    short* __restrict__ yT)
{
  __shared__ float xs[32][129];
  const int t  = threadIdx.x;
  const int k0 = blockIdx.x * 32;

  #pragma unroll
  for (int i = 0; i < 4; ++i) {
    int idx = i * 256 + t;
    int row = idx >> 5;
    int c4  = (idx & 31) * 4;
    f32x4 v = *(const f32x4*)(x + (size_t)(k0 + row) * DD + c4);
    xs[row][c4 + 0] = v[0]; xs[row][c4 + 1] = v[1];
    xs[row][c4 + 2] = v[2]; xs[row][c4 + 3] = v[3];
  }
  __syncthreads();

  const int kl = t & 31;
  const int g  = t >> 5;
  float acc[16];
  #pragma unroll
  for (int j = 0; j < 16; ++j) acc[j] = 0.f;

  for (int d = 0; d < 128; ++d) {
    float xv = xs[kl][d];
    const float* wr = W + d * DD + g * 16;
    f32x4 w0 = *(const f32x4*)(wr);
    f32x4 w1 = *(const f32x4*)(wr + 4);
    f32x4 w2 = *(const f32x4*)(wr + 8);
    f32x4 w3 = *(const f32x4*)(wr + 12);
    #pragma unroll
    for (int j = 0; j < 4; ++j) {
      acc[j]      += xv * w0[j];
      acc[4 + j]  += xv * w1[j];
      acc[8 + j]  += xv * w2[j];
      acc[12 + j] += xv * w3[j];
    }
  }
  #pragma unroll
  for (int j = 0; j < 16; ++j) {
    int n = g * 16 + j;
    yT[(size_t)n * NN + k0 + kl] = f2bf(acc[j]);
  }
}

// ---------------------------------------------------------------------------
// Kernel 2: partial[ks][m][n] = sum_{k in slice ks} A[m][k]*y[k][n]
//           degpart[ks][m]    = sum_{k in slice ks} A[m][k]
// Block geometry: 256 blocks = 32 m-groups x 8 k-slices; ks = blockIdx&7 so
// each XCD (round-robin b%8) owns ONE 256KB Y k-slice -> L2-resident.
// Block: 512 thr (8 waves); wave w owns 32 rows (2 16-row frags), sweeps the
// block's 1024-k slice. No cross-wave reduction (partials go to d_ws).
// ---------------------------------------------------------------------------
__global__ __launch_bounds__(512, 2) void gcn_main(
    const float* __restrict__ A, const short* __restrict__ yT,
    float* __restrict__ part, float* __restrict__ degpart)
{
  const int tid   = threadIdx.x;
  const int l     = tid & 63;
  const int w     = tid >> 6;
  const int ks    = blockIdx.x & 7;        // k-slice == XCD id (b%8)
  const int mg    = blockIdx.x >> 3;       // 0..31
  const int mbase = mg * 256 + w * 32;
  const int kbase = ks * 1024;
  const int l15   = l & 15;
  const int kl    = (l >> 4) * 8;

  const float* arow0 = A + (size_t)(mbase + l15) * NN;
  const float* arow1 = arow0 + (size_t)16 * NN;

  f32x4 acc[2][8];
  #pragma unroll
  for (int f = 0; f < 2; ++f)
    #pragma unroll
    for (int n = 0; n < 8; ++n) acc[f][n] = (f32x4)0.f;
  float deg0 = 0.f, deg1 = 0.f;

  #pragma unroll 2
  for (int s = 0; s < 32; ++s) {
    const int k0 = kbase + s * 32 + kl;

    f32x4 a0lo = __builtin_nontemporal_load((const f32x4*)(arow0 + k0));
    f32x4 a0hi = __builtin_nontemporal_load((const f32x4*)(arow0 + k0 + 4));
    f32x4 a1lo = __builtin_nontemporal_load((const f32x4*)(arow1 + k0));
    f32x4 a1hi = __builtin_nontemporal_load((const f32x4*)(arow1 + k0 + 4));

    bf16x8 b[8];
    #pragma unroll
    for (int n = 0; n < 8; ++n)
      b[n] = *(const bf16x8*)(yT + (size_t)(n * 16 + l15) * NN + k0);

    deg0 += (a0lo[0] + a0lo[1]) + (a0lo[2] + a0lo[3])
          + (a0hi[0] + a0hi[1]) + (a0hi[2] + a0hi[3]);
    deg1 += (a1lo[0] + a1lo[1]) + (a1lo[2] + a1lo[3])
          + (a1hi[0] + a1hi[1]) + (a1hi[2] + a1hi[3]);

    bf16x8 a0, a1;
    #pragma unroll
    for (int j = 0; j < 4; ++j) {
      a0[j]     = f2bf(a0lo[j]);
      a0[4 + j] = f2bf(a0hi[j]);
      a1[j]     = f2bf(a1lo[j]);
      a1[4 + j] = f2bf(a1hi[j]);
    }

    #pragma unroll
    for (int n = 0; n < 8; ++n) {
      acc[0][n] = __builtin_amdgcn_mfma_f32_16x16x32_bf16(a0, b[n], acc[0][n], 0, 0, 0);
      acc[1][n] = __builtin_amdgcn_mfma_f32_16x16x32_bf16(a1, b[n], acc[1][n], 0, 0, 0);
    }
  }

  // degree partials: reduce over the 4 k-offset lanes (xor 16, 32)
  deg0 += __shfl_xor(deg0, 16); deg0 += __shfl_xor(deg0, 32);
  deg1 += __shfl_xor(deg1, 16); deg1 += __shfl_xor(deg1, 32);
  if (l < 16) {
    degpart[(size_t)ks * NN + mbase + l]      = deg0;
    degpart[(size_t)ks * NN + mbase + 16 + l] = deg1;
  }

  // partial C tile -> d_ws (fp32, non-temporal; consumed by reduce kernel)
  float* pbase = part + (size_t)ks * NN * DD;
  #pragma unroll
  for (int f = 0; f < 2; ++f)
    #pragma unroll
    for (int n = 0; n < 8; ++n)
      #pragma unroll
      for (int i = 0; i < 4; ++i) {
        int row = mbase + f * 16 + (l >> 4) * 4 + i;
        int col = n * 16 + l15;
        __builtin_nontemporal_store(acc[f][n][i], pbase + (size_t)row * DD + col);
      }
}

// ---------------------------------------------------------------------------
// Kernel 3: out[m][n] = (sum_ks part[ks][m][n]) / (sum_ks degpart[ks][m])
// ---------------------------------------------------------------------------
__global__ __launch_bounds__(256) void reduce_kernel(
    const float* __restrict__ part, const float* __restrict__ degpart,
    float* __restrict__ out)
{
  const int idx = blockIdx.x * 256 + threadIdx.x;   // 0 .. 8192*32-1
  const int m   = idx >> 5;
  const int c4  = (idx & 31) * 4;

  f32x4 s = (f32x4)0.f;
  float d = 0.f;
  #pragma unroll
  for (int ks = 0; ks < 8; ++ks) {
    f32x4 v = *(const f32x4*)(part + (size_t)ks * NN * DD + (size_t)m * DD + c4);
    s[0] += v[0]; s[1] += v[1]; s[2] += v[2]; s[3] += v[3];
    d += degpart[(size_t)ks * NN + m];
  }
  f32x4 r;
  r[0] = s[0] / d; r[1] = s[1] / d; r[2] = s[2] / d; r[3] = s[3] / d;
  *(f32x4*)(out + (size_t)m * DD + c4) = r;
}

extern "C" void kernel_launch(void* const* d_in, const int* in_sizes, int n_in,
                              void* d_out, int out_size, void* d_ws, size_t ws_size,
                              hipStream_t stream) {
  const float* x = (const float*)d_in[0];   // [8192,128] fp32
  const float* A = (const float*)d_in[1];   // [8192,8192] fp32
  const float* W = (const float*)d_in[2];   // [128,128] fp32
  float* out = (float*)d_out;               // [8192,128] fp32

  // workspace layout
  char* ws = (char*)d_ws;
  short* yT      = (short*)ws;                          // 2 MB  bf16 [128][8192]
  float* part    = (float*)(ws + (2u << 20));           // 32 MB fp32 [8][8192][128]
  float* degpart = (float*)(ws + (2u << 20) + (32u << 20)); // 256 KB fp32 [8][8192]

  xw_kernel<<<256, 256, 0, stream>>>(x, W, yT);
  gcn_main<<<256, 512, 0, stream>>>(A, yT, part, degpart);
  reduce_kernel<<<1024, 256, 0, stream>>>(part, degpart, out);
}

// Round 4
// 102.477 us; speedup vs baseline: 1.4971x; 1.4971x over previous
//
#include <hip/hip_runtime.h>
#include <hip/hip_bf16.h>

#define NN 8192
#define DD 128

typedef __attribute__((ext_vector_type(4))) float f32x4;
typedef __attribute__((ext_vector_type(8))) short bf16x8;

__device__ __forceinline__ short f2bf(float f) {
  __hip_bfloat16 h = __float2bfloat16(f);
  return __builtin_bit_cast(short, h);
}

// async global->LDS, 16B per lane. LDS dest is wave-uniform base + lane*16
// (linear); global src is per-lane (carries the swizzle).
__device__ __forceinline__ void async_copy16(void* lds, const void* g) {
  __builtin_amdgcn_global_load_lds(
      (const __attribute__((address_space(1))) void*)g,
      (__attribute__((address_space(3))) void*)lds, 16, 0, 0);
}

// ---------------------------------------------------------------------------
// Kernel 1: yT[n][k] = sum_d x[k][d] * W[d][n]   (bf16, transposed)
// ---------------------------------------------------------------------------
__global__ __launch_bounds__(256) void xw_kernel(
    const float* __restrict__ x, const float* __restrict__ W,
    short* __restrict__ yT)
{
  __shared__ float xs[32][129];
  const int t  = threadIdx.x;
  const int k0 = blockIdx.x * 32;

  #pragma unroll
  for (int i = 0; i < 4; ++i) {
    int idx = i * 256 + t;
    int row = idx >> 5;
    int c4  = (idx & 31) * 4;
    f32x4 v = *(const f32x4*)(x + (size_t)(k0 + row) * DD + c4);
    xs[row][c4 + 0] = v[0]; xs[row][c4 + 1] = v[1];
    xs[row][c4 + 2] = v[2]; xs[row][c4 + 3] = v[3];
  }
  __syncthreads();

  const int kl = t & 31;
  const int g  = t >> 5;
  float acc[16];
  #pragma unroll
  for (int j = 0; j < 16; ++j) acc[j] = 0.f;

  for (int d = 0; d < 128; ++d) {
    float xv = xs[kl][d];
    const float* wr = W + d * DD + g * 16;
    f32x4 w0 = *(const f32x4*)(wr);
    f32x4 w1 = *(const f32x4*)(wr + 4);
    f32x4 w2 = *(const f32x4*)(wr + 8);
    f32x4 w3 = *(const f32x4*)(wr + 12);
    #pragma unroll
    for (int j = 0; j < 4; ++j) {
      acc[j]      += xv * w0[j];
      acc[4 + j]  += xv * w1[j];
      acc[8 + j]  += xv * w2[j];
      acc[12 + j] += xv * w3[j];
    }
  }
  #pragma unroll
  for (int j = 0; j < 16; ++j) {
    int n = g * 16 + j;
    yT[(size_t)n * NN + k0 + kl] = f2bf(acc[j]);
  }
}

// ---------------------------------------------------------------------------
// Kernel 2: partial[ks][m][n] = sum_{k in slice ks} A[m][k]*y[k][n]
//           degpart[ks][m]    = sum_{k in slice ks} A[m][k]
// 512 blocks = 64 row-groups x 8 k-slices (ks = b&7 == XCD id -> Y slice
// L2-resident). Block: 512 thr / 8 waves; 128 rows x 1024-k slice.
// Per K-step (32 k): global_load_lds stages A [128][32]f32 (16KB) and
// Y [128][32]bf16 (8KB), double-buffered; MLP comes from the async DMA
// (1KB in flight per stage instr), not from VGPR loads.
// Swizzle: LDS linear, source pre-swizzled + XOR on ds_read (both-sides).
//   A: 16B-group c holds global group c ^ (row&7)
//   Y: 16B-group c holds global group c ^ (row&3)
// ---------------------------------------------------------------------------
__global__ __launch_bounds__(512, 4) void gcn_main(
    const float* __restrict__ A, const short* __restrict__ yT,
    float* __restrict__ part, float* __restrict__ degpart)
{
  __shared__ float Abuf[2][128 * 32];   // 2 x 16 KB
  __shared__ short Ybuf[2][128 * 32];   // 2 x  8 KB

  const int tid   = threadIdx.x;
  const int l     = tid & 63;
  const int w     = tid >> 6;            // wave 0..7
  const int ks    = blockIdx.x & 7;      // k-slice == XCD id (b%8)
  const int mg    = blockIdx.x >> 3;     // 0..63
  const int R0    = mg * 128;
  const int kbase = ks * 1024;
  const int l15   = l & 15;
  const int kg    = l >> 4;              // 0..3 (k-group of 8)

  // --- staging lane constants (source pre-swizzle) ---
  const int a_r8  = l >> 3;                    // row in 8-row A chunk
  const int a_grp = (l & 7) ^ a_r8;            // global 16B group (of 8)
  const int y_r16 = l >> 2;                    // row in 16-row Y chunk
  const int y_grp = (l & 3) ^ (y_r16 & 3);     // global 16B group (of 4)

  const float* gA0 = A  + (size_t)(R0 + (w * 2 + 0) * 8 + a_r8) * NN + a_grp * 4;
  const float* gA1 = A  + (size_t)(R0 + (w * 2 + 1) * 8 + a_r8) * NN + a_grp * 4;
  const short* gY  = yT + (size_t)(w * 16 + y_r16) * NN + y_grp * 8;

  // --- compute-phase LDS offsets (read-side XOR matches source swizzle) ---
  const int arow    = w * 16 + l15;
  const int asw     = arow & 7;
  const int aoff_lo = arow * 32 + ((((kg << 1))     ^ asw) << 2);
  const int aoff_hi = arow * 32 + ((((kg << 1) | 1) ^ asw) << 2);
  const int yoff    = l15 * 32 + ((kg ^ (l15 & 3)) << 3);

  f32x4 acc[8];
  #pragma unroll
  for (int n = 0; n < 8; ++n) acc[n] = (f32x4)0.f;
  float deg = 0.f;

  // prologue: stage step 0
  {
    async_copy16(&Abuf[0][(w * 2 + 0) * 256], gA0 + kbase);
    async_copy16(&Abuf[0][(w * 2 + 1) * 256], gA1 + kbase);
    async_copy16(&Ybuf[0][w * 512],           gY  + kbase);
  }
  __syncthreads();   // implicit vmcnt(0): buffer 0 ready

  for (int s = 0; s < 32; ++s) {
    const int cur = s & 1;
    if (s < 31) {   // issue next-step stage; lands by the end-of-step barrier
      const int k = kbase + (s + 1) * 32;
      async_copy16(&Abuf[cur ^ 1][(w * 2 + 0) * 256], gA0 + k);
      async_copy16(&Abuf[cur ^ 1][(w * 2 + 1) * 256], gA1 + k);
      async_copy16(&Ybuf[cur ^ 1][w * 512],           gY  + k);
    }

    const float* Ab = Abuf[cur];
    const short* Yb = Ybuf[cur];

    f32x4 alo = *(const f32x4*)&Ab[aoff_lo];
    f32x4 ahi = *(const f32x4*)&Ab[aoff_hi];

    deg += (alo[0] + alo[1]) + (alo[2] + alo[3])
         + (ahi[0] + ahi[1]) + (ahi[2] + ahi[3]);

    bf16x8 a;
    #pragma unroll
    for (int j = 0; j < 4; ++j) {
      a[j]     = f2bf(alo[j]);
      a[4 + j] = f2bf(ahi[j]);
    }

    #pragma unroll
    for (int n = 0; n < 8; ++n) {
      bf16x8 b = *(const bf16x8*)&Yb[n * 512 + yoff];
      acc[n] = __builtin_amdgcn_mfma_f32_16x16x32_bf16(a, b, acc[n], 0, 0, 0);
    }

    __syncthreads();   // drains this step's stage (vmcnt 0) + lds reads
  }

  // --- degree: reduce over the 4 kg lane-groups (rows are l15-indexed) ---
  deg += __shfl_xor(deg, 16);
  deg += __shfl_xor(deg, 32);
  if (l < 16)
    degpart[(size_t)ks * NN + R0 + w * 16 + l] = deg;

  // --- partial C tile -> d_ws ---
  float* pbase = part + (size_t)ks * NN * DD + (size_t)(R0 + w * 16) * DD;
  #pragma unroll
  for (int n = 0; n < 8; ++n)
    #pragma unroll
    for (int i = 0; i < 4; ++i)
      __builtin_nontemporal_store(acc[n][i],
          pbase + (size_t)(kg * 4 + i) * DD + n * 16 + l15);
}

// ---------------------------------------------------------------------------
// Kernel 3: out[m][n] = (sum_ks part[ks][m][n]) / (sum_ks degpart[ks][m])
// ---------------------------------------------------------------------------
__global__ __launch_bounds__(256) void reduce_kernel(
    const float* __restrict__ part, const float* __restrict__ degpart,
    float* __restrict__ out)
{
  const int idx = blockIdx.x * 256 + threadIdx.x;   // 0 .. 8192*32-1
  const int m   = idx >> 5;
  const int c4  = (idx & 31) * 4;

  f32x4 s = (f32x4)0.f;
  float d = 0.f;
  #pragma unroll
  for (int ks = 0; ks < 8; ++ks) {
    f32x4 v = *(const f32x4*)(part + (size_t)ks * NN * DD + (size_t)m * DD + c4);
    s[0] += v[0]; s[1] += v[1]; s[2] += v[2]; s[3] += v[3];
    d += degpart[(size_t)ks * NN + m];
  }
  f32x4 r;
  r[0] = s[0] / d; r[1] = s[1] / d; r[2] = s[2] / d; r[3] = s[3] / d;
  *(f32x4*)(out + (size_t)m * DD + c4) = r;
}

extern "C" void kernel_launch(void* const* d_in, const int* in_sizes, int n_in,
                              void* d_out, int out_size, void* d_ws, size_t ws_size,
                              hipStream_t stream) {
  const float* x = (const float*)d_in[0];   // [8192,128] fp32
  const float* A = (const float*)d_in[1];   // [8192,8192] fp32
  const float* W = (const float*)d_in[2];   // [128,128] fp32
  float* out = (float*)d_out;               // [8192,128] fp32

  // workspace layout
  char* ws = (char*)d_ws;
  short* yT      = (short*)ws;                              // 2 MB  bf16 [128][8192]
  float* part    = (float*)(ws + (2u << 20));               // 32 MB fp32 [8][8192][128]
  float* degpart = (float*)(ws + (2u << 20) + (32u << 20)); // 256 KB fp32 [8][8192]

  xw_kernel<<<256, 256, 0, stream>>>(x, W, yT);
  gcn_main<<<512, 512, 0, stream>>>(A, yT, part, degpart);
  reduce_kernel<<<1024, 256, 0, stream>>>(part, degpart, out);
}

// Round 5
// 101.172 us; speedup vs baseline: 1.5164x; 1.0129x over previous
//
#include <hip/hip_runtime.h>
#include <hip/hip_bf16.h>

#define NN 8192
#define DD 128

typedef __attribute__((ext_vector_type(4))) float f32x4;
typedef __attribute__((ext_vector_type(8))) short bf16x8;

__device__ __forceinline__ short f2bf(float f) {
  __hip_bfloat16 h = __float2bfloat16(f);
  return __builtin_bit_cast(short, h);
}

// async global->LDS, 16B per lane. LDS dest is wave-uniform base + lane*16
// (linear); global src is per-lane (carries the swizzle).
__device__ __forceinline__ void async_copy16(void* lds, const void* g) {
  __builtin_amdgcn_global_load_lds(
      (const __attribute__((address_space(1))) void*)g,
      (__attribute__((address_space(3))) void*)lds, 16, 0, 0);
}

// ---------------------------------------------------------------------------
// Kernel 1: yT[n][k] = sum_d x[k][d] * W[d][n]   (bf16, transposed)
// ---------------------------------------------------------------------------
__global__ __launch_bounds__(256) void xw_kernel(
    const float* __restrict__ x, const float* __restrict__ W,
    short* __restrict__ yT)
{
  __shared__ float xs[32][129];
  const int t  = threadIdx.x;
  const int k0 = blockIdx.x * 32;

  #pragma unroll
  for (int i = 0; i < 4; ++i) {
    int idx = i * 256 + t;
    int row = idx >> 5;
    int c4  = (idx & 31) * 4;
    f32x4 v = *(const f32x4*)(x + (size_t)(k0 + row) * DD + c4);
    xs[row][c4 + 0] = v[0]; xs[row][c4 + 1] = v[1];
    xs[row][c4 + 2] = v[2]; xs[row][c4 + 3] = v[3];
  }
  __syncthreads();

  const int kl = t & 31;
  const int g  = t >> 5;
  float acc[16];
  #pragma unroll
  for (int j = 0; j < 16; ++j) acc[j] = 0.f;

  for (int d = 0; d < 128; ++d) {
    float xv = xs[kl][d];
    const float* wr = W + d * DD + g * 16;
    f32x4 w0 = *(const f32x4*)(wr);
    f32x4 w1 = *(const f32x4*)(wr + 4);
    f32x4 w2 = *(const f32x4*)(wr + 8);
    f32x4 w3 = *(const f32x4*)(wr + 12);
    #pragma unroll
    for (int j = 0; j < 4; ++j) {
      acc[j]      += xv * w0[j];
      acc[4 + j]  += xv * w1[j];
      acc[8 + j]  += xv * w2[j];
      acc[12 + j] += xv * w3[j];
    }
  }
  #pragma unroll
  for (int j = 0; j < 16; ++j) {
    int n = g * 16 + j;
    yT[(size_t)n * NN + k0 + kl] = f2bf(acc[j]);
  }
}

// ---------------------------------------------------------------------------
// Kernel 2: partial[ks][m][n] = sum_{k in slice ks} A[m][k]*y[k][n]
//           degpart[ks][m]    = sum_{k in slice ks} A[m][k]
// 512 blocks = 64 row-groups x 8 k-slices (ks = b&7 == XCD -> Y L2-resident).
// T3+T4: 3-deep LDS pipeline (72KB), raw s_barrier + per-wave counted vmcnt.
// Per wave per step: 3 global_load_lds (2xA 16B-lane rows, 1xY). 9 in flight
// after prologue; vmcnt(6) = own oldest step landed; barrier#1 = everyone's.
// barrier#2 after MFMA = all readers done -> restage that buffer for s+3.
// Prefetch for s+1,s+2 stays in flight ACROSS barriers (no vmcnt(0) drain).
// ---------------------------------------------------------------------------
__global__ __launch_bounds__(512, 4) void gcn_main(
    const float* __restrict__ A, const short* __restrict__ yT,
    float* __restrict__ part, float* __restrict__ degpart)
{
  __shared__ float Abuf[3][128 * 32];   // 3 x 16 KB
  __shared__ short Ybuf[3][128 * 32];   // 3 x  8 KB

  const int tid   = threadIdx.x;
  const int l     = tid & 63;
  const int w     = tid >> 6;            // wave 0..7
  const int ks    = blockIdx.x & 7;      // k-slice == XCD id (b%8)
  const int mg    = blockIdx.x >> 3;     // 0..63
  const int R0    = mg * 128;
  const int kbase = ks * 1024;
  const int l15   = l & 15;
  const int kg    = l >> 4;              // 0..3 (k-group of 8)

  // --- staging lane constants (source pre-swizzle) ---
  const int a_r8  = l >> 3;                    // row in 8-row A chunk
  const int a_grp = (l & 7) ^ a_r8;            // global 16B group (of 8)
  const int y_r16 = l >> 2;                    // row in 16-row Y chunk
  const int y_grp = (l & 3) ^ (y_r16 & 3);     // global 16B group (of 4)

  const float* gA0 = A  + (size_t)(R0 + (w * 2 + 0) * 8 + a_r8) * NN + a_grp * 4;
  const float* gA1 = A  + (size_t)(R0 + (w * 2 + 1) * 8 + a_r8) * NN + a_grp * 4;
  const short* gY  = yT + (size_t)(w * 16 + y_r16) * NN + y_grp * 8;

  // --- compute-phase LDS offsets (read-side XOR matches source swizzle) ---
  const int arow    = w * 16 + l15;
  const int asw     = arow & 7;
  const int aoff_lo = arow * 32 + ((((kg << 1))     ^ asw) << 2);
  const int aoff_hi = arow * 32 + ((((kg << 1) | 1) ^ asw) << 2);
  const int yoff    = l15 * 32 + ((kg ^ (l15 & 3)) << 3);

  f32x4 acc[8];
  #pragma unroll
  for (int n = 0; n < 8; ++n) acc[n] = (f32x4)0.f;
  float deg = 0.f;

#define STAGE(buf, step) do {                                        \
    const int _k = kbase + (step) * 32;                              \
    async_copy16(&Abuf[buf][(w * 2 + 0) * 256], gA0 + _k);           \
    async_copy16(&Abuf[buf][(w * 2 + 1) * 256], gA1 + _k);           \
    async_copy16(&Ybuf[buf][w * 512],           gY  + _k);           \
  } while (0)

  auto compute = [&](const float* Ab, const short* Yb) {
    f32x4 alo = *(const f32x4*)&Ab[aoff_lo];
    f32x4 ahi = *(const f32x4*)&Ab[aoff_hi];

    deg += (alo[0] + alo[1]) + (alo[2] + alo[3])
         + (ahi[0] + ahi[1]) + (ahi[2] + ahi[3]);

    bf16x8 a;
    #pragma unroll
    for (int j = 0; j < 4; ++j) {
      a[j]     = f2bf(alo[j]);
      a[4 + j] = f2bf(ahi[j]);
    }

    #pragma unroll
    for (int n = 0; n < 8; ++n) {
      bf16x8 b = *(const bf16x8*)&Yb[n * 512 + yoff];
      acc[n] = __builtin_amdgcn_mfma_f32_16x16x32_bf16(a, b, acc[n], 0, 0, 0);
    }
  };

  // prologue: fill the 3-deep pipe (9 DMA loads in flight per wave)
  STAGE(0, 0);
  STAGE(1, 1);
  STAGE(2, 2);

  // steady state: s = 0..29
  for (int st = 0; st < 30; st += 3) {
    #pragma unroll
    for (int j = 0; j < 3; ++j) {      // buffer index, compile-time after unroll
      asm volatile("s_waitcnt vmcnt(6)" ::: "memory");
      __builtin_amdgcn_s_barrier();
      compute(Abuf[j], Ybuf[j]);
      __builtin_amdgcn_s_barrier();
      __builtin_amdgcn_sched_barrier(0);
      if (st + j < 29)                 // stage step s+3 (exists for s <= 28)
        STAGE(j, st + j + 3);
    }
  }
  // s = 30 (buf 0): only step 31's 3 loads may remain younger
  asm volatile("s_waitcnt vmcnt(3)" ::: "memory");
  __builtin_amdgcn_s_barrier();
  compute(Abuf[0], Ybuf[0]);
  __builtin_amdgcn_s_barrier();
  // s = 31 (buf 1)
  asm volatile("s_waitcnt vmcnt(0)" ::: "memory");
  __builtin_amdgcn_s_barrier();
  compute(Abuf[1], Ybuf[1]);
#undef STAGE

  // --- degree: reduce over the 4 kg lane-groups (rows are l15-indexed) ---
  deg += __shfl_xor(deg, 16);
  deg += __shfl_xor(deg, 32);
  if (l < 16)
    degpart[(size_t)ks * NN + R0 + w * 16 + l] = deg;

  // --- partial C tile -> d_ws ---
  float* pbase = part + (size_t)ks * NN * DD + (size_t)(R0 + w * 16) * DD;
  #pragma unroll
  for (int n = 0; n < 8; ++n)
    #pragma unroll
    for (int i = 0; i < 4; ++i)
      __builtin_nontemporal_store(acc[n][i],
          pbase + (size_t)(kg * 4 + i) * DD + n * 16 + l15);
}

// ---------------------------------------------------------------------------
// Kernel 3: out[m][n] = (sum_ks part[ks][m][n]) / (sum_ks degpart[ks][m])
// ---------------------------------------------------------------------------
__global__ __launch_bounds__(256) void reduce_kernel(
    const float* __restrict__ part, const float* __restrict__ degpart,
    float* __restrict__ out)
{
  const int idx = blockIdx.x * 256 + threadIdx.x;   // 0 .. 8192*32-1
  const int m   = idx >> 5;
  const int c4  = (idx & 31) * 4;

  f32x4 s = (f32x4)0.f;
  float d = 0.f;
  #pragma unroll
  for (int ks = 0; ks < 8; ++ks) {
    f32x4 v = *(const f32x4*)(part + (size_t)ks * NN * DD + (size_t)m * DD + c4);
    s[0] += v[0]; s[1] += v[1]; s[2] += v[2]; s[3] += v[3];
    d += degpart[(size_t)ks * NN + m];
  }
  f32x4 r;
  r[0] = s[0] / d; r[1] = s[1] / d; r[2] = s[2] / d; r[3] = s[3] / d;
  *(f32x4*)(out + (size_t)m * DD + c4) = r;
}

extern "C" void kernel_launch(void* const* d_in, const int* in_sizes, int n_in,
                              void* d_out, int out_size, void* d_ws, size_t ws_size,
                              hipStream_t stream) {
  const float* x = (const float*)d_in[0];   // [8192,128] fp32
  const float* A = (const float*)d_in[1];   // [8192,8192] fp32
  const float* W = (const float*)d_in[2];   // [128,128] fp32
  float* out = (float*)d_out;               // [8192,128] fp32

  // workspace layout
  char* ws = (char*)d_ws;
  short* yT      = (short*)ws;                              // 2 MB  bf16 [128][8192]
  float* part    = (float*)(ws + (2u << 20));               // 32 MB fp32 [8][8192][128]
  float* degpart = (float*)(ws + (2u << 20) + (32u << 20)); // 256 KB fp32 [8][8192]

  xw_kernel<<<256, 256, 0, stream>>>(x, W, yT);
  gcn_main<<<512, 512, 0, stream>>>(A, yT, part, degpart);
  reduce_kernel<<<1024, 256, 0, stream>>>(part, degpart, out);
}